// Round 11
// baseline (285.392 us; speedup 1.0000x reference)
//
#include <hip/hip_runtime.h>
#include <stdint.h>

#define N_DET 200
#define HW 243200
#define NP 208
#define NT 13               // 16-row tiles (208/16)
#define KSTEPS 3800         // HW/64
#define GS 256              // K-split (= grid size)
#define SPB 15              // K-steps per block
#define TRI_TILES 91        // 13*14/2 upper-triangle tiles
#define PART_STRIDE (TRI_TILES * 256)   // f32 per block
#define LDS_STRIDE 72       // 64 + 8 pad (bf16 elems)
#define HWV (HW / 4)        // float4 per row
#define GATHER_VECS (N_DET * HWV)
#define NBLK 256
#define NTHR 832

typedef __attribute__((ext_vector_type(8))) short bf16x8v;
typedef __attribute__((ext_vector_type(4))) float f32x4;

__device__ __forceinline__ unsigned short f32_to_bf16(float f) {
    union { float f; uint32_t i; } v; v.f = f;
    uint32_t lsb = (v.i >> 16) & 1u;
    v.i += 0x7FFFu + lsb;          // round-to-nearest-even
    return (unsigned short)(v.i >> 16);
}

__device__ __forceinline__ uint4 pack8(const float4& a, const float4& b) {
    unsigned short u[8];
    u[0] = f32_to_bf16(a.x); u[1] = f32_to_bf16(a.y);
    u[2] = f32_to_bf16(a.z); u[3] = f32_to_bf16(a.w);
    u[4] = f32_to_bf16(b.x); u[5] = f32_to_bf16(b.y);
    u[6] = f32_to_bf16(b.z); u[7] = f32_to_bf16(b.w);
    return *(const uint4*)u;
}

struct NmsS {
    float sc[N_DET];   int lab[N_DET];   float ar[N_DET];
    int   order_[N_DET]; float sc_s[N_DET]; int lab_s[N_DET]; float ar_s[N_DET];
    float comp[N_DET]; float part[N_DET][4]; int ipart[N_DET][4];
    float nsc[N_DET];  int ord2[N_DET];
};
union SmemU {
    unsigned short gram[2][NP * LDS_STRIDE];   // 59,904 B (max member)
    NmsS nms;                                  // 14.4 KB
};

// Device-scope grid barrier: monotonic counter in d_ws (zeroed per call via
// hipMemsetAsync). __threadfence() release/acquire provides the buffer_wbl2 /
// buffer_inv cache maintenance that per-dispatch boundaries normally supply
// (per-XCD L2s are not coherent, G16).
__device__ __forceinline__ void grid_barrier(unsigned* bar, int use) {
    __syncthreads();
    if (threadIdx.x == 0) {
        __threadfence();   // release: drain + writeback L2
        __hip_atomic_fetch_add(bar, 1u, __ATOMIC_RELEASE, __HIP_MEMORY_SCOPE_AGENT);
        const unsigned target = (unsigned)NBLK * (unsigned)(use + 1);
        while (__hip_atomic_load(bar, __ATOMIC_ACQUIRE, __HIP_MEMORY_SCOPE_AGENT) < target)
            __builtin_amdgcn_s_sleep(8);
        __threadfence();   // acquire: invalidate stale L1/L2 lines
    }
    __syncthreads();
}

__global__ __launch_bounds__(NTHR) void mega_kernel(const float* __restrict__ masks,
                                                    const float* __restrict__ scores_in,
                                                    const int* __restrict__ labels,
                                                    float* __restrict__ out_scores,
                                                    float* __restrict__ out_labels,
                                                    float* __restrict__ out_masks,
                                                    float* __restrict__ out_keep,
                                                    float* __restrict__ partial,
                                                    float* __restrict__ gram,
                                                    unsigned* __restrict__ bar) {
    __shared__ SmemU smem;
    const int t = threadIdx.x;

    // ================= phase 1: K-split triangular Gram (EXACT R9 structure) ==========
    // LDS rows: 0..199 = bf16(masks), 200 = 1.0 (ones-row -> areas), 201..207 = 0.
    // f32 partials REQUIRED (bf16 partials -> rank swaps -> FAIL, round 5).
    {
        const int kb = blockIdx.x;
        const int s0 = kb * SPB;
        const int s1 = min(KSTEPS, s0 + SPB);

        f32x4 acc[NT];
#pragma unroll
        for (int j = 0; j < NT; ++j) acc[j] = (f32x4){0.f, 0.f, 0.f, 0.f};

        const int lane = t & 63, wv = t >> 6;
        const int frow = lane & 15;
        const int koff = (lane >> 4) * 8;
        const int srow = t >> 3;             // 0..103
        const int scol = (t & 7) * 8;

        const int r0 = srow, r1 = srow + 104;
        const float* src0 = masks + (size_t)r0 * HW + scol;
        const float* src1 = masks + (size_t)r1 * HW + scol;

        float4 f0a, f0b, f1a, f1b;

        if (s0 < s1) {
            const int k0 = s0 * 64;
            if (r0 < N_DET) { f0a = *(const float4*)(src0 + k0); f0b = *(const float4*)(src0 + k0 + 4); }
            if (r1 < N_DET) { f1a = *(const float4*)(src1 + k0); f1b = *(const float4*)(src1 + k0 + 4); }
            uint4 w0, w1;
            if (r0 < N_DET) w0 = pack8(f0a, f0b);
            else { const unsigned short fl = (r0 == N_DET) ? 0x3F80 : 0; unsigned short u[8];
#pragma unroll
                   for (int i = 0; i < 8; ++i) u[i] = fl; w0 = *(const uint4*)u; }
            if (r1 < N_DET) w1 = pack8(f1a, f1b);
            else { const unsigned short fl = (r1 == N_DET) ? 0x3F80 : 0; unsigned short u[8];
#pragma unroll
                   for (int i = 0; i < 8; ++i) u[i] = fl; w1 = *(const uint4*)u; }
            *(uint4*)&smem.gram[0][r0 * LDS_STRIDE + scol] = w0;
            *(uint4*)&smem.gram[0][r1 * LDS_STRIDE + scol] = w1;
            __syncthreads();

            int cur = 0;
            for (int s = s0; s < s1; ++s) {
                const bool has_next = (s + 1 < s1);
                if (has_next) {
                    const int kn = (s + 1) * 64;
                    if (r0 < N_DET) { f0a = *(const float4*)(src0 + kn); f0b = *(const float4*)(src0 + kn + 4); }
                    if (r1 < N_DET) { f1a = *(const float4*)(src1 + kn); f1b = *(const float4*)(src1 + kn + 4); }
                }

                const unsigned short* bp = &smem.gram[cur][0];
                bf16x8v a0 = *(const bf16x8v*)&bp[(wv * 16 + frow) * LDS_STRIDE + koff];
                bf16x8v a1 = *(const bf16x8v*)&bp[(wv * 16 + frow) * LDS_STRIDE + 32 + koff];
#pragma unroll
                for (int jt = 0; jt < NT; ++jt) {
                    if (jt < wv) continue;           // wave-uniform triangle skip
                    bf16x8v b0, b1;
                    if (jt == wv) { b0 = a0; b1 = a1; }
                    else {
                        b0 = *(const bf16x8v*)&bp[(jt * 16 + frow) * LDS_STRIDE + koff];
                        b1 = *(const bf16x8v*)&bp[(jt * 16 + frow) * LDS_STRIDE + 32 + koff];
                    }
                    acc[jt] = __builtin_amdgcn_mfma_f32_16x16x32_bf16(a0, b0, acc[jt], 0, 0, 0);
                    acc[jt] = __builtin_amdgcn_mfma_f32_16x16x32_bf16(a1, b1, acc[jt], 0, 0, 0);
                }

                if (has_next) {
                    uint4 w0n, w1n;
                    if (r0 < N_DET) w0n = pack8(f0a, f0b);
                    else { const unsigned short fl = (r0 == N_DET) ? 0x3F80 : 0; unsigned short u[8];
#pragma unroll
                           for (int i = 0; i < 8; ++i) u[i] = fl; w0n = *(const uint4*)u; }
                    if (r1 < N_DET) w1n = pack8(f1a, f1b);
                    else { const unsigned short fl = (r1 == N_DET) ? 0x3F80 : 0; unsigned short u[8];
#pragma unroll
                           for (int i = 0; i < 8; ++i) u[i] = fl; w1n = *(const uint4*)u; }
                    *(uint4*)&smem.gram[cur ^ 1][r0 * LDS_STRIDE + scol] = w0n;
                    *(uint4*)&smem.gram[cur ^ 1][r1 * LDS_STRIDE + scol] = w1n;
                }
                __syncthreads();
                cur ^= 1;
            }
        }

        float* pp = partial + (size_t)kb * PART_STRIDE;
        const int tbase = wv * 13 - (wv * (wv - 1)) / 2 - wv;
        const int row16 = (lane >> 4) * 4;
        const int col16 = lane & 15;
#pragma unroll
        for (int jt = 0; jt < NT; ++jt) {
            if (jt < wv) continue;
            const int tile = tbase + jt;
#pragma unroll
            for (int r = 0; r < 4; ++r)
                pp[tile * 256 + (row16 + r) * 16 + col16] = acc[jt][r];
        }
    }

    grid_barrier(bar, 0);

    // ================= phase 2: reduce partials (91 blocks, f32, mirrored) ============
    if (blockIdx.x < TRI_TILES && t < 256) {
        int tau = blockIdx.x, tr = 0;
        while (tau >= NT - tr) { tau -= NT - tr; ++tr; }
        const int tc = tr + tau;
        const float* p = partial + blockIdx.x * 256 + t;
        float s = 0.f;
#pragma unroll 32
        for (int g = 0; g < GS; ++g) s += p[(size_t)g * PART_STRIDE];
        const int r = tr * 16 + (t >> 4);
        const int c = tc * 16 + (t & 15);
        gram[r * NP + c] = s;
        if (tr != tc) gram[c * NP + r] = s;
    }

    grid_barrier(bar, 1);

    // ================= phase 3: sort + decay + re-sort (block 0, 4-way split) =========
    // Combines are integer sums / fmax / fmin -> bit-exact under split;
    // expf expression byte-identical (ordering noise = failure mode, round 5).
    if (blockIdx.x == 0) {
        NmsS& S = smem.nms;
        const int i4 = t >> 2, s4 = t & 3;   // valid for t < 800

        if (t < N_DET) {
            S.sc[t]  = scores_in[t];
            S.lab[t] = labels[t];
            S.ar[t]  = gram[N_DET * NP + t];   // ones-row => area
        }
        __syncthreads();

        if (t < 800) {
            const float si = S.sc[i4];
            int r = 0;
            for (int j = s4; j < N_DET; j += 4) {
                const float sj = S.sc[j];
                if (sj > si || (sj == si && j < i4)) ++r;
            }
            S.ipart[i4][s4] = r;
        }
        __syncthreads();
        if (t < N_DET) {
            const int r = S.ipart[t][0] + S.ipart[t][1] + S.ipart[t][2] + S.ipart[t][3];
            S.order_[r] = t;
        }
        __syncthreads();
        if (t < N_DET) { const int o = S.order_[t]; S.sc_s[t] = S.sc[o]; S.lab_s[t] = S.lab[o]; S.ar_s[t] = S.ar[o]; }
        __syncthreads();

        if (t < 800) {
            float m = 0.f;
            const int oj = S.order_[i4];
            const float aj = S.ar_s[i4];
            const int lj = S.lab_s[i4];
            for (int i = s4; i < i4; i += 4) {
                if (S.lab_s[i] == lj) {
                    const float g = gram[S.order_[i] * NP + oj];
                    const float iou = g / (S.ar_s[i] + aj - g);
                    m = fmaxf(m, iou);
                }
            }
            S.part[i4][s4] = m;
        }
        __syncthreads();
        if (t < N_DET)
            S.comp[t] = fmaxf(fmaxf(S.part[t][0], S.part[t][1]), fmaxf(S.part[t][2], S.part[t][3]));
        __syncthreads();

        if (t < 800) {
            float mn = 1e30f;
            const int oj = S.order_[i4];
            const float aj = S.ar_s[i4];
            const int lj = S.lab_s[i4];
            for (int i = s4; i < N_DET; i += 4) {
                float d = 0.f;
                if (i < i4 && S.lab_s[i] == lj) {
                    const float g = gram[S.order_[i] * NP + oj];
                    d = g / (S.ar_s[i] + aj - g);
                }
                const float c = S.comp[i];
                const float val = expf(-2.0f * (d * d - c * c));
                mn = fminf(mn, val);
            }
            S.part[i4][s4] = mn;
        }
        __syncthreads();
        if (t < N_DET) {
            const float mn = fminf(fminf(S.part[t][0], S.part[t][1]), fminf(S.part[t][2], S.part[t][3]));
            S.nsc[t] = S.sc_s[t] * mn;
        }
        __syncthreads();

        if (t < 800) {
            const float si = S.nsc[i4];
            int r = 0;
            for (int k = s4; k < N_DET; k += 4) {
                const float sk = S.nsc[k];
                if (sk > si || (sk == si && k < i4)) ++r;
            }
            S.ipart[i4][s4] = r;
        }
        __syncthreads();
        if (t < N_DET) {
            const int r = S.ipart[t][0] + S.ipart[t][1] + S.ipart[t][2] + S.ipart[t][3];
            S.ord2[r] = t;
        }
        __syncthreads();

        if (t < N_DET) {
            const int jj = S.ord2[t];
            out_scores[t] = S.nsc[jj];
            out_labels[t] = (float)S.lab_s[jj];
            out_keep[t]   = (float)S.order_[jj];
        }
    }

    grid_barrier(bar, 2);

    // ================= phase 4: gather (all blocks; plain loads + nt stores) ==========
    {
        const f32x4* msk = (const f32x4*)masks;
        f32x4* om = (f32x4*)out_masks;
        const int stride = NBLK * NTHR;
        for (int i = blockIdx.x * NTHR + t; i < GATHER_VECS; i += stride) {
            const int r = i / HWV;
            const int c = i - r * HWV;
            const int src = (int)out_keep[r];
            const f32x4 v = msk[(size_t)src * HWV + c];
            __builtin_nontemporal_store(v, &om[i]);
        }
    }
}

extern "C" void kernel_launch(void* const* d_in, const int* in_sizes, int n_in,
                              void* d_out, int out_size, void* d_ws, size_t ws_size,
                              hipStream_t stream) {
    const float* masks  = (const float*)d_in[0];
    const float* scores = (const float*)d_in[1];
    const int*   labels = (const int*)d_in[2];
    float* out = (float*)d_out;

    // Output layout (f32): scores[200] | labels[200] | masks[200*HW] | keep[200]
    float* out_scores = out;
    float* out_labels = out + N_DET;
    float* out_masks  = out + 2 * N_DET;
    float* out_keep   = out + 2 * N_DET + (size_t)N_DET * HW;

    // Scratch inside the not-yet-written masks output region (194.6 MB):
    // partial 23.85 MB + gram 43264 f32. Phase-4 gather overwrites it last.
    float* partial = out_masks;
    float* gram    = out_masks + (size_t)GS * PART_STRIDE;
    unsigned* bar  = (unsigned*)d_ws;   // barrier counter (zeroed below each call)

    hipMemsetAsync(bar, 0, 64, stream);
    mega_kernel<<<NBLK, NTHR, 0, stream>>>(masks, scores, labels,
                                           out_scores, out_labels, out_masks, out_keep,
                                           partial, gram, bar);
}

// Round 12
// 207.598 us; speedup vs baseline: 1.3747x; 1.3747x over previous
//
#include <hip/hip_runtime.h>
#include <stdint.h>

#define N_DET 200
#define HW 243200
#define NP 208
#define NT 13               // 16-row tiles (208/16)
#define KSTEPS 3800         // HW/64
#define GS 256              // K-split (= grid size)
#define SPB 15              // K-steps per block
#define TRI_TILES 91        // 13*14/2 upper-triangle tiles
#define PART_STRIDE (TRI_TILES * 256)   // f32 per block
#define LDS_STRIDE 72       // 64 + 8 pad (bf16 elems)
#define HWV (HW / 4)        // float4 per row
#define GATHER_VECS (N_DET * HWV)
#define NBLK 256
#define NTHR 832

typedef __attribute__((ext_vector_type(8))) short bf16x8v;
typedef __attribute__((ext_vector_type(4))) float f32x4;

__device__ __forceinline__ unsigned short f32_to_bf16(float f) {
    union { float f; uint32_t i; } v; v.f = f;
    uint32_t lsb = (v.i >> 16) & 1u;
    v.i += 0x7FFFu + lsb;          // round-to-nearest-even
    return (unsigned short)(v.i >> 16);
}

__device__ __forceinline__ uint4 pack8(const float4& a, const float4& b) {
    unsigned short u[8];
    u[0] = f32_to_bf16(a.x); u[1] = f32_to_bf16(a.y);
    u[2] = f32_to_bf16(a.z); u[3] = f32_to_bf16(a.w);
    u[4] = f32_to_bf16(b.x); u[5] = f32_to_bf16(b.y);
    u[6] = f32_to_bf16(b.z); u[7] = f32_to_bf16(b.w);
    return *(const uint4*)u;
}

struct NmsS {
    float sc[N_DET];   int lab[N_DET];   float ar[N_DET];
    int   order_[N_DET]; float sc_s[N_DET]; int lab_s[N_DET]; float ar_s[N_DET];
    float comp[N_DET]; float part[N_DET][4]; int ipart[N_DET][4];
    float nsc[N_DET];  int ord2[N_DET];
};
union SmemU {
    unsigned short gram[2][NP * LDS_STRIDE];   // 59,904 B (max member)
    NmsS nms;                                  // 14.4 KB
};

// Device-scope grid barrier (R11 protocol, FIXED POLL):
//  - release __threadfence (thread 0; block's stores are already in local L2 via
//    the pre-barrier s_waitcnt vmcnt(0); wbl2 flushes them XCD-wide)
//  - spin with RELAXED agent loads (reads coherence point, NO L2 invalidate --
//    R11's acquire-per-poll caused an invalidation storm: 0.6 TB/s, +150 us)
//  - one acquire __threadfence on exit.
__device__ __forceinline__ void grid_barrier(unsigned* bar, int use) {
    __syncthreads();
    if (threadIdx.x == 0) {
        __threadfence();   // release: writeback local XCD L2
        __hip_atomic_fetch_add(bar, 1u, __ATOMIC_RELEASE, __HIP_MEMORY_SCOPE_AGENT);
        const unsigned target = (unsigned)NBLK * (unsigned)(use + 1);
        while (__hip_atomic_load(bar, __ATOMIC_RELAXED, __HIP_MEMORY_SCOPE_AGENT) < target)
            __builtin_amdgcn_s_sleep(64);   // ~1.7us between polls
        __threadfence();   // acquire: invalidate stale L1/L2 once
    }
    __syncthreads();
}

__global__ __launch_bounds__(NTHR) void mega_kernel(const float* __restrict__ masks,
                                                    const float* __restrict__ scores_in,
                                                    const int* __restrict__ labels,
                                                    float* __restrict__ out_scores,
                                                    float* __restrict__ out_labels,
                                                    float* __restrict__ out_masks,
                                                    float* __restrict__ out_keep,
                                                    float* __restrict__ partial,
                                                    float* __restrict__ gram,
                                                    unsigned* __restrict__ bar) {
    __shared__ SmemU smem;
    const int t = threadIdx.x;

    // ================= phase 1: K-split triangular Gram (EXACT R9 structure) ==========
    // LDS rows: 0..199 = bf16(masks), 200 = 1.0 (ones-row -> areas), 201..207 = 0.
    // f32 partials REQUIRED (bf16 partials -> rank swaps -> FAIL, round 5).
    {
        const int kb = blockIdx.x;
        const int s0 = kb * SPB;
        const int s1 = min(KSTEPS, s0 + SPB);

        f32x4 acc[NT];
#pragma unroll
        for (int j = 0; j < NT; ++j) acc[j] = (f32x4){0.f, 0.f, 0.f, 0.f};

        const int lane = t & 63, wv = t >> 6;
        const int frow = lane & 15;
        const int koff = (lane >> 4) * 8;
        const int srow = t >> 3;             // 0..103
        const int scol = (t & 7) * 8;

        const int r0 = srow, r1 = srow + 104;
        const float* src0 = masks + (size_t)r0 * HW + scol;
        const float* src1 = masks + (size_t)r1 * HW + scol;

        float4 f0a, f0b, f1a, f1b;

        if (s0 < s1) {
            const int k0 = s0 * 64;
            if (r0 < N_DET) { f0a = *(const float4*)(src0 + k0); f0b = *(const float4*)(src0 + k0 + 4); }
            if (r1 < N_DET) { f1a = *(const float4*)(src1 + k0); f1b = *(const float4*)(src1 + k0 + 4); }
            uint4 w0, w1;
            if (r0 < N_DET) w0 = pack8(f0a, f0b);
            else { const unsigned short fl = (r0 == N_DET) ? 0x3F80 : 0; unsigned short u[8];
#pragma unroll
                   for (int i = 0; i < 8; ++i) u[i] = fl; w0 = *(const uint4*)u; }
            if (r1 < N_DET) w1 = pack8(f1a, f1b);
            else { const unsigned short fl = (r1 == N_DET) ? 0x3F80 : 0; unsigned short u[8];
#pragma unroll
                   for (int i = 0; i < 8; ++i) u[i] = fl; w1 = *(const uint4*)u; }
            *(uint4*)&smem.gram[0][r0 * LDS_STRIDE + scol] = w0;
            *(uint4*)&smem.gram[0][r1 * LDS_STRIDE + scol] = w1;
            __syncthreads();

            int cur = 0;
            for (int s = s0; s < s1; ++s) {
                const bool has_next = (s + 1 < s1);
                if (has_next) {
                    const int kn = (s + 1) * 64;
                    if (r0 < N_DET) { f0a = *(const float4*)(src0 + kn); f0b = *(const float4*)(src0 + kn + 4); }
                    if (r1 < N_DET) { f1a = *(const float4*)(src1 + kn); f1b = *(const float4*)(src1 + kn + 4); }
                }

                const unsigned short* bp = &smem.gram[cur][0];
                bf16x8v a0 = *(const bf16x8v*)&bp[(wv * 16 + frow) * LDS_STRIDE + koff];
                bf16x8v a1 = *(const bf16x8v*)&bp[(wv * 16 + frow) * LDS_STRIDE + 32 + koff];
#pragma unroll
                for (int jt = 0; jt < NT; ++jt) {
                    if (jt < wv) continue;           // wave-uniform triangle skip
                    bf16x8v b0, b1;
                    if (jt == wv) { b0 = a0; b1 = a1; }
                    else {
                        b0 = *(const bf16x8v*)&bp[(jt * 16 + frow) * LDS_STRIDE + koff];
                        b1 = *(const bf16x8v*)&bp[(jt * 16 + frow) * LDS_STRIDE + 32 + koff];
                    }
                    acc[jt] = __builtin_amdgcn_mfma_f32_16x16x32_bf16(a0, b0, acc[jt], 0, 0, 0);
                    acc[jt] = __builtin_amdgcn_mfma_f32_16x16x32_bf16(a1, b1, acc[jt], 0, 0, 0);
                }

                if (has_next) {
                    uint4 w0n, w1n;
                    if (r0 < N_DET) w0n = pack8(f0a, f0b);
                    else { const unsigned short fl = (r0 == N_DET) ? 0x3F80 : 0; unsigned short u[8];
#pragma unroll
                           for (int i = 0; i < 8; ++i) u[i] = fl; w0n = *(const uint4*)u; }
                    if (r1 < N_DET) w1n = pack8(f1a, f1b);
                    else { const unsigned short fl = (r1 == N_DET) ? 0x3F80 : 0; unsigned short u[8];
#pragma unroll
                           for (int i = 0; i < 8; ++i) u[i] = fl; w1n = *(const uint4*)u; }
                    *(uint4*)&smem.gram[cur ^ 1][r0 * LDS_STRIDE + scol] = w0n;
                    *(uint4*)&smem.gram[cur ^ 1][r1 * LDS_STRIDE + scol] = w1n;
                }
                __syncthreads();
                cur ^= 1;
            }
        }

        float* pp = partial + (size_t)kb * PART_STRIDE;
        const int tbase = wv * 13 - (wv * (wv - 1)) / 2 - wv;
        const int row16 = (lane >> 4) * 4;
        const int col16 = lane & 15;
#pragma unroll
        for (int jt = 0; jt < NT; ++jt) {
            if (jt < wv) continue;
            const int tile = tbase + jt;
#pragma unroll
            for (int r = 0; r < 4; ++r)
                pp[tile * 256 + (row16 + r) * 16 + col16] = acc[jt][r];
        }
    }

    grid_barrier(bar, 0);

    // ===== phase 2: reduce partials (all 256 blocks, coalesced; g-order = R9 bit-exact) =====
    if (t < TRI_TILES) {
        const int e = blockIdx.x * TRI_TILES + t;   // 0..23295, contiguous per block
        const int tile = e >> 8, idx = e & 255;
        int tau = tile, tr = 0;
        while (tau >= NT - tr) { tau -= NT - tr; ++tr; }
        const int tc = tr + tau;
        const float* p = partial + tile * 256 + idx;
        float s = 0.f;
#pragma unroll 32
        for (int g = 0; g < GS; ++g) s += p[(size_t)g * PART_STRIDE];
        const int r = tr * 16 + (idx >> 4);
        const int c = tc * 16 + (idx & 15);
        gram[r * NP + c] = s;
        if (tr != tc) gram[c * NP + r] = s;
    }

    grid_barrier(bar, 1);

    // ================= phase 3: sort + decay + re-sort (block 0, 4-way split) =========
    // Combines are integer sums / fmax / fmin -> bit-exact under split;
    // expf expression byte-identical (ordering noise = failure mode, round 5).
    if (blockIdx.x == 0) {
        NmsS& S = smem.nms;
        const int i4 = t >> 2, s4 = t & 3;   // valid for t < 800

        if (t < N_DET) {
            S.sc[t]  = scores_in[t];
            S.lab[t] = labels[t];
            S.ar[t]  = gram[N_DET * NP + t];   // ones-row => area
        }
        __syncthreads();

        if (t < 800) {
            const float si = S.sc[i4];
            int r = 0;
            for (int j = s4; j < N_DET; j += 4) {
                const float sj = S.sc[j];
                if (sj > si || (sj == si && j < i4)) ++r;
            }
            S.ipart[i4][s4] = r;
        }
        __syncthreads();
        if (t < N_DET) {
            const int r = S.ipart[t][0] + S.ipart[t][1] + S.ipart[t][2] + S.ipart[t][3];
            S.order_[r] = t;
        }
        __syncthreads();
        if (t < N_DET) { const int o = S.order_[t]; S.sc_s[t] = S.sc[o]; S.lab_s[t] = S.lab[o]; S.ar_s[t] = S.ar[o]; }
        __syncthreads();

        if (t < 800) {
            float m = 0.f;
            const int oj = S.order_[i4];
            const float aj = S.ar_s[i4];
            const int lj = S.lab_s[i4];
            for (int i = s4; i < i4; i += 4) {
                if (S.lab_s[i] == lj) {
                    const float g = gram[S.order_[i] * NP + oj];
                    const float iou = g / (S.ar_s[i] + aj - g);
                    m = fmaxf(m, iou);
                }
            }
            S.part[i4][s4] = m;
        }
        __syncthreads();
        if (t < N_DET)
            S.comp[t] = fmaxf(fmaxf(S.part[t][0], S.part[t][1]), fmaxf(S.part[t][2], S.part[t][3]));
        __syncthreads();

        if (t < 800) {
            float mn = 1e30f;
            const int oj = S.order_[i4];
            const float aj = S.ar_s[i4];
            const int lj = S.lab_s[i4];
            for (int i = s4; i < N_DET; i += 4) {
                float d = 0.f;
                if (i < i4 && S.lab_s[i] == lj) {
                    const float g = gram[S.order_[i] * NP + oj];
                    d = g / (S.ar_s[i] + aj - g);
                }
                const float c = S.comp[i];
                const float val = expf(-2.0f * (d * d - c * c));
                mn = fminf(mn, val);
            }
            S.part[i4][s4] = mn;
        }
        __syncthreads();
        if (t < N_DET) {
            const float mn = fminf(fminf(S.part[t][0], S.part[t][1]), fminf(S.part[t][2], S.part[t][3]));
            S.nsc[t] = S.sc_s[t] * mn;
        }
        __syncthreads();

        if (t < 800) {
            const float si = S.nsc[i4];
            int r = 0;
            for (int k = s4; k < N_DET; k += 4) {
                const float sk = S.nsc[k];
                if (sk > si || (sk == si && k < i4)) ++r;
            }
            S.ipart[i4][s4] = r;
        }
        __syncthreads();
        if (t < N_DET) {
            const int r = S.ipart[t][0] + S.ipart[t][1] + S.ipart[t][2] + S.ipart[t][3];
            S.ord2[r] = t;
        }
        __syncthreads();

        if (t < N_DET) {
            const int jj = S.ord2[t];
            out_scores[t] = S.nsc[jj];
            out_labels[t] = (float)S.lab_s[jj];
            out_keep[t]   = (float)S.order_[jj];
        }
    }

    grid_barrier(bar, 2);

    // ================= phase 4: gather (all blocks; plain loads + nt stores) ==========
    {
        const f32x4* msk = (const f32x4*)masks;
        f32x4* om = (f32x4*)out_masks;
        const int stride = NBLK * NTHR;
        for (int i = blockIdx.x * NTHR + t; i < GATHER_VECS; i += stride) {
            const int r = i / HWV;
            const int c = i - r * HWV;
            const int src = (int)out_keep[r];
            const f32x4 v = msk[(size_t)src * HWV + c];
            __builtin_nontemporal_store(v, &om[i]);
        }
    }
}

extern "C" void kernel_launch(void* const* d_in, const int* in_sizes, int n_in,
                              void* d_out, int out_size, void* d_ws, size_t ws_size,
                              hipStream_t stream) {
    const float* masks  = (const float*)d_in[0];
    const float* scores = (const float*)d_in[1];
    const int*   labels = (const int*)d_in[2];
    float* out = (float*)d_out;

    // Output layout (f32): scores[200] | labels[200] | masks[200*HW] | keep[200]
    float* out_scores = out;
    float* out_labels = out + N_DET;
    float* out_masks  = out + 2 * N_DET;
    float* out_keep   = out + 2 * N_DET + (size_t)N_DET * HW;

    // Scratch inside the not-yet-written masks output region (194.6 MB):
    // partial 23.85 MB + gram 43264 f32. Phase-4 gather overwrites it last.
    float* partial = out_masks;
    float* gram    = out_masks + (size_t)GS * PART_STRIDE;
    unsigned* bar  = (unsigned*)d_ws;   // barrier counter (zeroed below each call)

    hipMemsetAsync(bar, 0, 64, stream);
    mega_kernel<<<NBLK, NTHR, 0, stream>>>(masks, scores, labels,
                                           out_scores, out_labels, out_masks, out_keep,
                                           partial, gram, bar);
}

// Round 13
// 152.803 us; speedup vs baseline: 1.8677x; 1.3586x over previous
//
#include <hip/hip_runtime.h>
#include <stdint.h>

#define N_DET 200
#define HW 243200
#define NP 208
#define NT 13               // 16-row tiles (208/16)
#define KSTEPS 3800         // HW/64
#define GS 512              // K-split blocks: 2 blocks/CU (MLP: 2x in-flight loads per CU)
#define TRI_TILES 91        // 13*14/2 upper-triangle tiles
#define PART_STRIDE (TRI_TILES * 256)   // f32 per block
#define LDS_STRIDE 72       // 64 + 8 pad (bf16 elems)
#define HWV (HW / 4)        // float4 per row
#define GATHER_VECS (N_DET * HWV)

typedef __attribute__((ext_vector_type(8))) short bf16x8v;
typedef __attribute__((ext_vector_type(4))) float f32x4;

__device__ __forceinline__ unsigned short f32_to_bf16(float f) {
    union { float f; uint32_t i; } v; v.f = f;
    uint32_t lsb = (v.i >> 16) & 1u;
    v.i += 0x7FFFu + lsb;          // round-to-nearest-even
    return (unsigned short)(v.i >> 16);
}

__device__ __forceinline__ uint4 pack8(const float4& a, const float4& b) {
    unsigned short u[8];
    u[0] = f32_to_bf16(a.x); u[1] = f32_to_bf16(a.y);
    u[2] = f32_to_bf16(a.z); u[3] = f32_to_bf16(a.w);
    u[4] = f32_to_bf16(b.x); u[5] = f32_to_bf16(b.y);
    u[6] = f32_to_bf16(b.z); u[7] = f32_to_bf16(b.w);
    return *(const uint4*)u;
}

// ---------------- kernel 1: K-split triangular Gram via bf16 MFMA ----------------
// R9-proven structure (dbuf LDS, 1 barrier/step, reg prefetch 1 step ahead).
// GS=512 -> 2 blocks/CU: 53 KB in-flight loads/CU + inter-block phase overlap.
// LDS rows: 0..199 = bf16(masks), 200 = 1.0 (ones-row -> areas), 201..207 = 0.
// f32 partials REQUIRED (bf16 partials -> rank swaps -> FAIL, round 5).
__global__ __launch_bounds__(832) void gram_kernel(const float* __restrict__ masks,
                                                   float* __restrict__ partial) {
    __shared__ unsigned short lds[2][NP * LDS_STRIDE];   // 59,904 B
    const int kb = blockIdx.x;
    const int s0 = (kb * KSTEPS) / GS;          // proportional K-partition (7-8 steps)
    const int s1 = ((kb + 1) * KSTEPS) / GS;

    f32x4 acc[NT];
#pragma unroll
    for (int j = 0; j < NT; ++j) acc[j] = (f32x4){0.f, 0.f, 0.f, 0.f};

    const int t = threadIdx.x;
    const int lane = t & 63, wv = t >> 6;
    const int frow = lane & 15;          // row-in-tile for A/B fragments
    const int koff = (lane >> 4) * 8;    // k-offset within 32-wide half-step
    const int srow = t >> 3;             // staging row 0..103 (then +104)
    const int scol = (t & 7) * 8;        // staging col

    const int r0 = srow, r1 = srow + 104;
    const float* src0 = masks + (size_t)r0 * HW + scol;
    const float* src1 = masks + (size_t)r1 * HW + scol;

    float4 f0a, f0b, f1a, f1b;           // prefetch regs (static names: no scratch)

    if (s0 < s1) {
        const int k0 = s0 * 64;
        if (r0 < N_DET) { f0a = *(const float4*)(src0 + k0); f0b = *(const float4*)(src0 + k0 + 4); }
        if (r1 < N_DET) { f1a = *(const float4*)(src1 + k0); f1b = *(const float4*)(src1 + k0 + 4); }
        uint4 w0, w1;
        if (r0 < N_DET) w0 = pack8(f0a, f0b);
        else { const unsigned short fl = (r0 == N_DET) ? 0x3F80 : 0; unsigned short u[8];
#pragma unroll
               for (int i = 0; i < 8; ++i) u[i] = fl; w0 = *(const uint4*)u; }
        if (r1 < N_DET) w1 = pack8(f1a, f1b);
        else { const unsigned short fl = (r1 == N_DET) ? 0x3F80 : 0; unsigned short u[8];
#pragma unroll
               for (int i = 0; i < 8; ++i) u[i] = fl; w1 = *(const uint4*)u; }
        *(uint4*)&lds[0][r0 * LDS_STRIDE + scol] = w0;
        *(uint4*)&lds[0][r1 * LDS_STRIDE + scol] = w1;
        __syncthreads();

        int cur = 0;
        for (int s = s0; s < s1; ++s) {
            const bool has_next = (s + 1 < s1);
            if (has_next) {
                const int kn = (s + 1) * 64;
                if (r0 < N_DET) { f0a = *(const float4*)(src0 + kn); f0b = *(const float4*)(src0 + kn + 4); }
                if (r1 < N_DET) { f1a = *(const float4*)(src1 + kn); f1b = *(const float4*)(src1 + kn + 4); }
            }

            const unsigned short* bp = &lds[cur][0];
            bf16x8v a0 = *(const bf16x8v*)&bp[(wv * 16 + frow) * LDS_STRIDE + koff];
            bf16x8v a1 = *(const bf16x8v*)&bp[(wv * 16 + frow) * LDS_STRIDE + 32 + koff];
#pragma unroll
            for (int jt = 0; jt < NT; ++jt) {
                if (jt < wv) continue;               // wave-uniform triangle skip
                bf16x8v b0, b1;
                if (jt == wv) { b0 = a0; b1 = a1; }
                else {
                    b0 = *(const bf16x8v*)&bp[(jt * 16 + frow) * LDS_STRIDE + koff];
                    b1 = *(const bf16x8v*)&bp[(jt * 16 + frow) * LDS_STRIDE + 32 + koff];
                }
                acc[jt] = __builtin_amdgcn_mfma_f32_16x16x32_bf16(a0, b0, acc[jt], 0, 0, 0);
                acc[jt] = __builtin_amdgcn_mfma_f32_16x16x32_bf16(a1, b1, acc[jt], 0, 0, 0);
            }

            if (has_next) {
                uint4 w0n, w1n;
                if (r0 < N_DET) w0n = pack8(f0a, f0b);
                else { const unsigned short fl = (r0 == N_DET) ? 0x3F80 : 0; unsigned short u[8];
#pragma unroll
                       for (int i = 0; i < 8; ++i) u[i] = fl; w0n = *(const uint4*)u; }
                if (r1 < N_DET) w1n = pack8(f1a, f1b);
                else { const unsigned short fl = (r1 == N_DET) ? 0x3F80 : 0; unsigned short u[8];
#pragma unroll
                       for (int i = 0; i < 8; ++i) u[i] = fl; w1n = *(const uint4*)u; }
                *(uint4*)&lds[cur ^ 1][r0 * LDS_STRIDE + scol] = w0n;
                *(uint4*)&lds[cur ^ 1][r1 * LDS_STRIDE + scol] = w1n;
            }
            __syncthreads();
            cur ^= 1;
        }
    }

    // store triangle tiles, tile-contiguous, f32
    float* pp = partial + (size_t)kb * PART_STRIDE;
    const int tbase = wv * 13 - (wv * (wv - 1)) / 2 - wv;   // tri(wv,jt) = tbase + jt
    const int row16 = (lane >> 4) * 4;
    const int col16 = lane & 15;
#pragma unroll
    for (int jt = 0; jt < NT; ++jt) {
        if (jt < wv) continue;
        const int tile = tbase + jt;
#pragma unroll
        for (int r = 0; r < 4; ++r)
            pp[tile * 256 + (row16 + r) * 16 + col16] = acc[jt][r];
    }
}

// ---------------- kernel 2: reduce K-split partials (f32, mirrored) ----------------
__global__ void reduce_kernel(const float* __restrict__ partial,
                              float* __restrict__ gram) {
    const int tr = blockIdx.x, tc = blockIdx.y;
    if (tc < tr) return;
    const int tile = tr * 13 - (tr * (tr - 1)) / 2 + (tc - tr);
    const int idx = threadIdx.x;
    const float* p = partial + tile * 256 + idx;
    float s = 0.f;
#pragma unroll 32
    for (int g = 0; g < GS; ++g) s += p[(size_t)g * PART_STRIDE];
    const int r = tr * 16 + (idx >> 4);
    const int c = tc * 16 + (idx & 15);
    gram[r * NP + c] = s;
    if (tr != tc) gram[c * NP + r] = s;
}

// ---------------- kernel 3: sort + matrix-NMS decay + re-sort ----------------
// O(N) loops 5-way split; combine via integer rank-sums / fmax / fmin (bit-exact);
// expf expression byte-identical (ordering noise = failure mode, round 5).
__global__ __launch_bounds__(1024) void nms_kernel(const float* __restrict__ scores_in,
                                                   const int* __restrict__ labels,
                                                   const float* __restrict__ gram,
                                                   float* __restrict__ out_scores,
                                                   float* __restrict__ out_labels,
                                                   float* __restrict__ out_keep) {
    __shared__ float sc[N_DET];
    __shared__ int   lab[N_DET];
    __shared__ float ar[N_DET];
    __shared__ int   order_[N_DET];
    __shared__ float sc_s[N_DET];
    __shared__ int   lab_s[N_DET];
    __shared__ float ar_s[N_DET];
    __shared__ float comp[N_DET];
    __shared__ float part[N_DET][5];
    __shared__ int   ipart[N_DET][5];
    __shared__ float nsc[N_DET];
    __shared__ int   ord2[N_DET];

    const int t = threadIdx.x;
    const int i5 = t / 5, s5 = t - i5 * 5;   // valid for t < 1000

    if (t < N_DET) {
        sc[t]  = scores_in[t];
        lab[t] = labels[t];
        ar[t]  = gram[N_DET * NP + t];   // ones-row => area
    }
    __syncthreads();

    if (t < 1000) {
        const float si = sc[i5];
        int r = 0;
        for (int j = s5; j < N_DET; j += 5) {
            const float sj = sc[j];
            if (sj > si || (sj == si && j < i5)) ++r;
        }
        ipart[i5][s5] = r;
    }
    __syncthreads();
    if (t < N_DET) {
        const int r = ipart[t][0] + ipart[t][1] + ipart[t][2] + ipart[t][3] + ipart[t][4];
        order_[r] = t;
    }
    __syncthreads();
    if (t < N_DET) { const int o = order_[t]; sc_s[t] = sc[o]; lab_s[t] = lab[o]; ar_s[t] = ar[o]; }
    __syncthreads();

    if (t < 1000) {
        float m = 0.f;
        const int oj = order_[i5];
        const float aj = ar_s[i5];
        const int lj = lab_s[i5];
        for (int i = s5; i < i5; i += 5) {
            if (lab_s[i] == lj) {
                const float g = gram[order_[i] * NP + oj];
                const float iou = g / (ar_s[i] + aj - g);
                m = fmaxf(m, iou);
            }
        }
        part[i5][s5] = m;
    }
    __syncthreads();
    if (t < N_DET)
        comp[t] = fmaxf(fmaxf(fmaxf(part[t][0], part[t][1]), fmaxf(part[t][2], part[t][3])), part[t][4]);
    __syncthreads();

    if (t < 1000) {
        float mn = 1e30f;
        const int oj = order_[i5];
        const float aj = ar_s[i5];
        const int lj = lab_s[i5];
        for (int i = s5; i < N_DET; i += 5) {
            float d = 0.f;
            if (i < i5 && lab_s[i] == lj) {
                const float g = gram[order_[i] * NP + oj];
                d = g / (ar_s[i] + aj - g);
            }
            const float c = comp[i];
            const float val = expf(-2.0f * (d * d - c * c));
            mn = fminf(mn, val);
        }
        part[i5][s5] = mn;
    }
    __syncthreads();
    if (t < N_DET) {
        const float mn = fminf(fminf(fminf(part[t][0], part[t][1]), fminf(part[t][2], part[t][3])), part[t][4]);
        nsc[t] = sc_s[t] * mn;
    }
    __syncthreads();

    if (t < 1000) {
        const float si = nsc[i5];
        int r = 0;
        for (int k = s5; k < N_DET; k += 5) {
            const float sk = nsc[k];
            if (sk > si || (sk == si && k < i5)) ++r;
        }
        ipart[i5][s5] = r;
    }
    __syncthreads();
    if (t < N_DET) {
        const int r = ipart[t][0] + ipart[t][1] + ipart[t][2] + ipart[t][3] + ipart[t][4];
        ord2[r] = t;
    }
    __syncthreads();

    if (t < N_DET) {
        const int jj = ord2[t];
        out_scores[t] = nsc[jj];
        out_labels[t] = (float)lab_s[jj];
        out_keep[t]   = (float)order_[jj];
    }
}

// ---------------- kernel 4: grid-stride gather ----------------
// Reads: PLAIN cached loads (masks L3-resident after gram; R12 FETCH proves gather
// reads hit L3). Writes: nt-store (output never re-read; don't evict masks).
__global__ void gather_kernel(const f32x4* __restrict__ masks,
                              const float* __restrict__ keep,
                              f32x4* __restrict__ out_masks) {
    const int stride = gridDim.x * blockDim.x;
    for (int i = blockIdx.x * blockDim.x + threadIdx.x; i < GATHER_VECS; i += stride) {
        const int r = i / HWV;
        const int c = i - r * HWV;
        const int src = (int)keep[r];
        const f32x4 v = masks[(size_t)src * HWV + c];
        __builtin_nontemporal_store(v, &out_masks[i]);
    }
}

extern "C" void kernel_launch(void* const* d_in, const int* in_sizes, int n_in,
                              void* d_out, int out_size, void* d_ws, size_t ws_size,
                              hipStream_t stream) {
    const float* masks  = (const float*)d_in[0];
    const float* scores = (const float*)d_in[1];
    const int*   labels = (const int*)d_in[2];
    float* out = (float*)d_out;

    // Output layout (f32): scores[200] | labels[200] | masks[200*HW] | keep[200]
    float* out_scores = out;
    float* out_labels = out + N_DET;
    float* out_masks  = out + 2 * N_DET;
    float* out_keep   = out + 2 * N_DET + (size_t)N_DET * HW;

    // Scratch inside the not-yet-written masks output region (194.6 MB).
    // partial: GS*PART_STRIDE f32 = 47.7 MB, gram: 43264 f32. Gather overwrites last.
    float* partial = out_masks;
    float* gram    = out_masks + (size_t)GS * PART_STRIDE;

    gram_kernel<<<GS, 832, 0, stream>>>(masks, partial);
    reduce_kernel<<<dim3(13, 13), 256, 0, stream>>>(partial, gram);
    nms_kernel<<<1, 1024, 0, stream>>>(scores, labels, gram,
                                       out_scores, out_labels, out_keep);
    gather_kernel<<<2048, 256, 0, stream>>>((const f32x4*)masks, out_keep, (f32x4*)out_masks);
}

// Round 14
// 135.674 us; speedup vs baseline: 2.1035x; 1.1262x over previous
//
#include <hip/hip_runtime.h>
#include <stdint.h>

#define N_DET 200
#define HW 243200
#define NP 208
#define NT 13               // 16-row tiles (208/16)
#define KSTEPS 3800         // HW/64
#define GS 256              // K-split blocks (1/CU -- R13 proved 2/CU regresses)
#define SPB 15              // K-steps per block
#define TRI_TILES 91        // 13*14/2 upper-triangle tiles
#define PART_STRIDE (TRI_TILES * 256)   // f32 per block
#define LDS_STRIDE 72       // 64 + 8 pad (bf16 elems)
#define HWV (HW / 4)        // float4 per row
#define GATHER_VECS (N_DET * HWV)

typedef __attribute__((ext_vector_type(8))) short bf16x8v;
typedef __attribute__((ext_vector_type(4))) float f32x4;

__device__ __forceinline__ unsigned short f32_to_bf16(float f) {
    union { float f; uint32_t i; } v; v.f = f;
    uint32_t lsb = (v.i >> 16) & 1u;
    v.i += 0x7FFFu + lsb;          // round-to-nearest-even
    return (unsigned short)(v.i >> 16);
}

__device__ __forceinline__ uint4 pack8(const float4& a, const float4& b) {
    unsigned short u[8];
    u[0] = f32_to_bf16(a.x); u[1] = f32_to_bf16(a.y);
    u[2] = f32_to_bf16(a.z); u[3] = f32_to_bf16(a.w);
    u[4] = f32_to_bf16(b.x); u[5] = f32_to_bf16(b.y);
    u[6] = f32_to_bf16(b.z); u[7] = f32_to_bf16(b.w);
    return *(const uint4*)u;
}

// ---------------- kernel 1: K-split triangular Gram via bf16 MFMA ----------------
// R9 structure + DEPTH-2 register prefetch: two 64B load batches (A,B) in flight;
// pack of batch X waits only on X's loads (compiler emits vmcnt(4)), so 4 loads
// stay outstanding across each barrier -> ~2 phases of latency cover instead of 1.
// LDS rows: 0..199 = bf16(masks), 200 = 1.0 (ones-row -> areas), 201..207 = 0.
// f32 partials REQUIRED (bf16 partials -> rank swaps -> FAIL, round 5).
__global__ __launch_bounds__(832) void gram_kernel(const float* __restrict__ masks,
                                                   float* __restrict__ partial) {
    __shared__ unsigned short lds[2][NP * LDS_STRIDE];   // 59,904 B
    const int kb = blockIdx.x;
    const int s0 = kb * SPB;
    const int s1 = min(KSTEPS, s0 + SPB);

    f32x4 acc[NT];
#pragma unroll
    for (int j = 0; j < NT; ++j) acc[j] = (f32x4){0.f, 0.f, 0.f, 0.f};

    const int t = threadIdx.x;
    const int lane = t & 63, wv = t >> 6;
    const int frow = lane & 15;          // row-in-tile for A/B fragments
    const int koff = (lane >> 4) * 8;    // k-offset within 32-wide half-step
    const int srow = t >> 3;             // staging row 0..103 (then +104)
    const int scol = (t & 7) * 8;        // staging col

    const int r0 = srow, r1 = srow + 104;
    const bool lv0 = (r0 < N_DET), lv1 = (r1 < N_DET);
    const float* src0 = masks + (size_t)r0 * HW + scol;
    const float* src1 = masks + (size_t)r1 * HW + scol;
    unsigned short flv0, flv1;
    { unsigned short f0 = (r0 == N_DET) ? 0x3F80 : 0; flv0 = f0;
      unsigned short f1 = (r1 == N_DET) ? 0x3F80 : 0; flv1 = f1; }

    // two independent prefetch batches, static names (rule #20: no dynamic indexing)
    float4 a0, a1, a2, a3;   // batch A
    float4 b0, b1, b2, b3;   // batch B

#define LOAD_A(S) do { const int k_ = (S) * 64;                                      \
        if (lv0) { a0 = *(const float4*)(src0 + k_); a1 = *(const float4*)(src0 + k_ + 4); } \
        if (lv1) { a2 = *(const float4*)(src1 + k_); a3 = *(const float4*)(src1 + k_ + 4); } } while (0)
#define LOAD_B(S) do { const int k_ = (S) * 64;                                      \
        if (lv0) { b0 = *(const float4*)(src0 + k_); b1 = *(const float4*)(src0 + k_ + 4); } \
        if (lv1) { b2 = *(const float4*)(src1 + k_); b3 = *(const float4*)(src1 + k_ + 4); } } while (0)
#define PACK_WRITE(P0, P1, P2, P3, BUF) do {                                         \
        uint4 w0_, w1_;                                                              \
        if (lv0) w0_ = pack8(P0, P1);                                                \
        else { unsigned short u_[8];                                                 \
               _Pragma("unroll") for (int i_ = 0; i_ < 8; ++i_) u_[i_] = flv0;       \
               w0_ = *(const uint4*)u_; }                                            \
        if (lv1) w1_ = pack8(P2, P3);                                                \
        else { unsigned short u_[8];                                                 \
               _Pragma("unroll") for (int i_ = 0; i_ < 8; ++i_) u_[i_] = flv1;       \
               w1_ = *(const uint4*)u_; }                                            \
        *(uint4*)&lds[BUF][r0 * LDS_STRIDE + scol] = w0_;                            \
        *(uint4*)&lds[BUF][r1 * LDS_STRIDE + scol] = w1_; } while (0)

#define MFMA_PHASE(BUF) do {                                                         \
        const unsigned short* bp = &lds[BUF][0];                                     \
        bf16x8v fa0 = *(const bf16x8v*)&bp[(wv * 16 + frow) * LDS_STRIDE + koff];    \
        bf16x8v fa1 = *(const bf16x8v*)&bp[(wv * 16 + frow) * LDS_STRIDE + 32 + koff]; \
        _Pragma("unroll")                                                            \
        for (int jt = 0; jt < NT; ++jt) {                                            \
            if (jt < wv) continue;                                                   \
            bf16x8v fb0, fb1;                                                        \
            if (jt == wv) { fb0 = fa0; fb1 = fa1; }                                  \
            else {                                                                   \
                fb0 = *(const bf16x8v*)&bp[(jt * 16 + frow) * LDS_STRIDE + koff];    \
                fb1 = *(const bf16x8v*)&bp[(jt * 16 + frow) * LDS_STRIDE + 32 + koff]; \
            }                                                                        \
            acc[jt] = __builtin_amdgcn_mfma_f32_16x16x32_bf16(fa0, fb0, acc[jt], 0, 0, 0); \
            acc[jt] = __builtin_amdgcn_mfma_f32_16x16x32_bf16(fa1, fb1, acc[jt], 0, 0, 0); \
        } } while (0)

    // prologue: A=s0 staged to buf0; B=s0+1 issued (stays in flight)
    LOAD_A(s0);
    if (s0 + 1 < s1) LOAD_B(s0 + 1);
    PACK_WRITE(a0, a1, a2, a3, 0);       // waits only on A's loads
    __syncthreads();

    int cur = 0;
    for (int s = s0; s < s1; s += 2) {
        // even iter: compute buf[cur] (data s); stage B (s+1) -> cur^1; refill A (s+2)
        if (s + 2 < s1) LOAD_A(s + 2);
        MFMA_PHASE(cur);
        if (s + 1 < s1) PACK_WRITE(b0, b1, b2, b3, cur ^ 1);   // vmcnt covers B only
        __syncthreads();
        cur ^= 1;
        if (s + 1 >= s1) break;

        // odd iter: compute buf[cur] (data s+1); stage A (s+2) -> cur^1; refill B (s+3)
        if (s + 3 < s1) LOAD_B(s + 3);
        MFMA_PHASE(cur);
        if (s + 2 < s1) PACK_WRITE(a0, a1, a2, a3, cur ^ 1);   // vmcnt covers A only
        __syncthreads();
        cur ^= 1;
    }

#undef LOAD_A
#undef LOAD_B
#undef PACK_WRITE
#undef MFMA_PHASE

    // store triangle tiles, tile-contiguous, f32
    float* pp = partial + (size_t)kb * PART_STRIDE;
    const int tbase = wv * 13 - (wv * (wv - 1)) / 2 - wv;   // tri(wv,jt) = tbase + jt
    const int row16 = (lane >> 4) * 4;
    const int col16 = lane & 15;
#pragma unroll
    for (int jt = 0; jt < NT; ++jt) {
        if (jt < wv) continue;
        const int tile = tbase + jt;
#pragma unroll
        for (int r = 0; r < 4; ++r)
            pp[tile * 256 + (row16 + r) * 16 + col16] = acc[jt][r];
    }
}

// ---------------- kernel 2: reduce K-split partials (f32, mirrored) ----------------
__global__ void reduce_kernel(const float* __restrict__ partial,
                              float* __restrict__ gram) {
    const int tr = blockIdx.x, tc = blockIdx.y;
    if (tc < tr) return;
    const int tile = tr * 13 - (tr * (tr - 1)) / 2 + (tc - tr);
    const int idx = threadIdx.x;
    const float* p = partial + tile * 256 + idx;
    float s = 0.f;
#pragma unroll 32
    for (int g = 0; g < GS; ++g) s += p[(size_t)g * PART_STRIDE];
    const int r = tr * 16 + (idx >> 4);
    const int c = tc * 16 + (idx & 15);
    gram[r * NP + c] = s;
    if (tr != tc) gram[c * NP + r] = s;
}

// ---------------- kernel 3: sort + matrix-NMS decay + re-sort ----------------
// O(N) loops 5-way split; combine via integer rank-sums / fmax / fmin (bit-exact);
// expf expression byte-identical (ordering noise = failure mode, round 5).
__global__ __launch_bounds__(1024) void nms_kernel(const float* __restrict__ scores_in,
                                                   const int* __restrict__ labels,
                                                   const float* __restrict__ gram,
                                                   float* __restrict__ out_scores,
                                                   float* __restrict__ out_labels,
                                                   float* __restrict__ out_keep) {
    __shared__ float sc[N_DET];
    __shared__ int   lab[N_DET];
    __shared__ float ar[N_DET];
    __shared__ int   order_[N_DET];
    __shared__ float sc_s[N_DET];
    __shared__ int   lab_s[N_DET];
    __shared__ float ar_s[N_DET];
    __shared__ float comp[N_DET];
    __shared__ float part[N_DET][5];
    __shared__ int   ipart[N_DET][5];
    __shared__ float nsc[N_DET];
    __shared__ int   ord2[N_DET];

    const int t = threadIdx.x;
    const int i5 = t / 5, s5 = t - i5 * 5;   // valid for t < 1000

    if (t < N_DET) {
        sc[t]  = scores_in[t];
        lab[t] = labels[t];
        ar[t]  = gram[N_DET * NP + t];   // ones-row => area
    }
    __syncthreads();

    if (t < 1000) {
        const float si = sc[i5];
        int r = 0;
        for (int j = s5; j < N_DET; j += 5) {
            const float sj = sc[j];
            if (sj > si || (sj == si && j < i5)) ++r;
        }
        ipart[i5][s5] = r;
    }
    __syncthreads();
    if (t < N_DET) {
        const int r = ipart[t][0] + ipart[t][1] + ipart[t][2] + ipart[t][3] + ipart[t][4];
        order_[r] = t;
    }
    __syncthreads();
    if (t < N_DET) { const int o = order_[t]; sc_s[t] = sc[o]; lab_s[t] = lab[o]; ar_s[t] = ar[o]; }
    __syncthreads();

    if (t < 1000) {
        float m = 0.f;
        const int oj = order_[i5];
        const float aj = ar_s[i5];
        const int lj = lab_s[i5];
        for (int i = s5; i < i5; i += 5) {
            if (lab_s[i] == lj) {
                const float g = gram[order_[i] * NP + oj];
                const float iou = g / (ar_s[i] + aj - g);
                m = fmaxf(m, iou);
            }
        }
        part[i5][s5] = m;
    }
    __syncthreads();
    if (t < N_DET)
        comp[t] = fmaxf(fmaxf(fmaxf(part[t][0], part[t][1]), fmaxf(part[t][2], part[t][3])), part[t][4]);
    __syncthreads();

    if (t < 1000) {
        float mn = 1e30f;
        const int oj = order_[i5];
        const float aj = ar_s[i5];
        const int lj = lab_s[i5];
        for (int i = s5; i < N_DET; i += 5) {
            float d = 0.f;
            if (i < i5 && lab_s[i] == lj) {
                const float g = gram[order_[i] * NP + oj];
                d = g / (ar_s[i] + aj - g);
            }
            const float c = comp[i];
            const float val = expf(-2.0f * (d * d - c * c));
            mn = fminf(mn, val);
        }
        part[i5][s5] = mn;
    }
    __syncthreads();
    if (t < N_DET) {
        const float mn = fminf(fminf(fminf(part[t][0], part[t][1]), fminf(part[t][2], part[t][3])), part[t][4]);
        nsc[t] = sc_s[t] * mn;
    }
    __syncthreads();

    if (t < 1000) {
        const float si = nsc[i5];
        int r = 0;
        for (int k = s5; k < N_DET; k += 5) {
            const float sk = nsc[k];
            if (sk > si || (sk == si && k < i5)) ++r;
        }
        ipart[i5][s5] = r;
    }
    __syncthreads();
    if (t < N_DET) {
        const int r = ipart[t][0] + ipart[t][1] + ipart[t][2] + ipart[t][3] + ipart[t][4];
        ord2[r] = t;
    }
    __syncthreads();

    if (t < N_DET) {
        const int jj = ord2[t];
        out_scores[t] = nsc[jj];
        out_labels[t] = (float)lab_s[jj];
        out_keep[t]   = (float)order_[jj];
    }
}

// ---------------- kernel 4: grid-stride gather ----------------
// Reads: PLAIN cached loads (masks L3-resident after gram; R12 FETCH proves gather
// reads hit L3). Writes: nt-store (output never re-read; don't evict masks).
__global__ void gather_kernel(const f32x4* __restrict__ masks,
                              const float* __restrict__ keep,
                              f32x4* __restrict__ out_masks) {
    const int stride = gridDim.x * blockDim.x;
    for (int i = blockIdx.x * blockDim.x + threadIdx.x; i < GATHER_VECS; i += stride) {
        const int r = i / HWV;
        const int c = i - r * HWV;
        const int src = (int)keep[r];
        const f32x4 v = masks[(size_t)src * HWV + c];
        __builtin_nontemporal_store(v, &out_masks[i]);
    }
}

extern "C" void kernel_launch(void* const* d_in, const int* in_sizes, int n_in,
                              void* d_out, int out_size, void* d_ws, size_t ws_size,
                              hipStream_t stream) {
    const float* masks  = (const float*)d_in[0];
    const float* scores = (const float*)d_in[1];
    const int*   labels = (const int*)d_in[2];
    float* out = (float*)d_out;

    // Output layout (f32): scores[200] | labels[200] | masks[200*HW] | keep[200]
    float* out_scores = out;
    float* out_labels = out + N_DET;
    float* out_masks  = out + 2 * N_DET;
    float* out_keep   = out + 2 * N_DET + (size_t)N_DET * HW;

    // Scratch inside the not-yet-written masks output region (194.6 MB).
    // partial: GS*PART_STRIDE f32 = 23.85 MB, gram: 43264 f32. Gather overwrites last.
    float* partial = out_masks;
    float* gram    = out_masks + (size_t)GS * PART_STRIDE;

    gram_kernel<<<GS, 832, 0, stream>>>(masks, partial);
    reduce_kernel<<<dim3(13, 13), 256, 0, stream>>>(partial, gram);
    nms_kernel<<<1, 1024, 0, stream>>>(scores, labels, gram,
                                       out_scores, out_labels, out_keep);
    gather_kernel<<<2048, 256, 0, stream>>>((const f32x4*)masks, out_keep, (f32x4*)out_masks);
}